// Round 10
// baseline (76.001 us; speedup 1.0000x reference)
//
#include <hip/hip_runtime.h>

#define DIM    256
#define NROWS  8192
#define NHALF  4096
#define NTILE  64                          // 8192 / 128 tiles per dim
#define NBLK   ((NTILE * (NTILE + 1)) / 2) // 2080 triangular tiles
#define GRID2  (NBLK / 2)                  // 1040 blocks, 2 tiles each
#define RSTRIDE 128                        // z4 row stride in bytes (256 fp4)

using i32x4  = __attribute__((ext_vector_type(4))) int;
using i32x8  = __attribute__((ext_vector_type(8))) int;
using f32x16 = __attribute__((ext_vector_type(16))) float;

struct i32x8_pair { i32x4 lo, hi; };

// fp4 e2m1 RNE quantizer for pre-scaled input (representable {0,.5,1,1.5,2,3,4,6})
__device__ __forceinline__ unsigned fp4q(float v) {
  float a = fabsf(v);
  unsigned s = (__builtin_bit_cast(unsigned, v) >> 31) << 3;
  unsigned c = a < 0.25f ? 0u : a < 0.75f ? 1u : a < 1.25f ? 2u : a < 1.75f ? 3u
             : a < 2.50f ? 4u : a < 3.50f ? 5u : a < 5.00f ? 6u : 7u;
  return s | c;
}

// ---- kernel 1: row-normalize x (fp32) -> z4 (fp4 e2m1, x16 scale), 1 wave/row.
__global__ __launch_bounds__(256) void normalize_k(const float* __restrict__ x,
                                                   unsigned char* __restrict__ z4) {
  const int row  = blockIdx.x * 4 + (threadIdx.x >> 6);
  const int lane = threadIdx.x & 63;
  float4 v = ((const float4*)(x + (size_t)row * DIM))[lane];
  float ss = v.x * v.x + v.y * v.y + v.z * v.z + v.w * v.w;
#pragma unroll
  for (int off = 32; off > 0; off >>= 1) ss += __shfl_xor(ss, off, 64);
  float rn = rsqrtf(fmaxf(ss, 1e-24f)) * 16.0f;   // pre-apply 2^4 (MX scale 2^-4)
  unsigned c0 = fp4q(v.x * rn), c1 = fp4q(v.y * rn);
  unsigned c2 = fp4q(v.z * rn), c3 = fp4q(v.w * rn);
  // element 2i in low nibble, 2i+1 in high nibble; lane covers elems 4l..4l+3
  unsigned short pk = (unsigned short)((c0 | (c1 << 4)) | ((c2 | (c3 << 4)) << 8));
  ((unsigned short*)(z4 + (size_t)row * RSTRIDE))[lane] = pk;
}

// ---- kernel 2: Gram exp-sum over upper-triangular 128x128 tiles, MX-fp4.
// TWO tiles per block (amortizes dispatch/drain/store/reduce fixed costs);
// full K=256 staged per tile (A+B = 32 KB -> 4 blocks/CU, one barrier/tile).
__global__ __launch_bounds__(256, 4) void gram_k(const unsigned char* __restrict__ z4,
                                                 double2* __restrict__ partial) {
  __shared__ unsigned char As[128 * RSTRIDE];   // 16 KB
  __shared__ unsigned char Bs[128 * RSTRIDE];   // 16 KB
  __shared__ double redS[4], redD[4];

  const int tid   = threadIdx.x;
  const int lane  = tid & 63;
  const int w     = tid >> 6;
  const int wr    = w >> 1, wc = w & 1;     // 2x2 wave grid, 64x64 each
  const int l31   = lane & 31;
  const int khalf = lane >> 5;              // K-half selector for 32x32 frags

  float Sthr = 0.0f, Dthr = 0.0f;           // per-thread weighted accumulators

  for (int sub = 0; sub < 2; ++sub) {
    const int bid = blockIdx.x * 2 + sub;
    // linear tile id -> (bi, bj), bi <= bj
    int bi = (int)((129.0 - sqrt(129.0 * 129.0 - 8.0 * (double)bid)) * 0.5);
    while ((bi * (129 - bi)) / 2 > bid) --bi;
    while (((bi + 1) * (128 - bi)) / 2 <= bid) ++bi;
    const int bj = bi + (bid - (bi * (129 - bi)) / 2);

    const size_t rowA0 = (size_t)bi * 128;
    const size_t rowB0 = (size_t)bj * 128;

    // stage 128 rows x 128 B (fp4) for A and B via global_load_lds, 16B/lane.
    // LDS 16B-chunk cb holds global chunk cb ^ (row&7) (swizzle applied on
    // the global side: glds dest = wave-uniform base + lane*16).
#pragma unroll
    for (int i = 0; i < 4; ++i) {
      int c   = i * 256 + tid;              // 0..1023 -> (row, chunk)
      int row = c >> 3;                     // 0..127
      int cb  = c & 7;
      int gcb = cb ^ (row & 7);
      const unsigned char* ga = z4 + (rowA0 + row) * RSTRIDE + gcb * 16;
      const unsigned char* gb = z4 + (rowB0 + row) * RSTRIDE + gcb * 16;
      __builtin_amdgcn_global_load_lds(
          (const __attribute__((address_space(1))) void*)ga,
          (__attribute__((address_space(3))) void*)&As[(size_t)(i * 256 + (tid & ~63)) * 16],
          16, 0, 0);
      __builtin_amdgcn_global_load_lds(
          (const __attribute__((address_space(1))) void*)gb,
          (__attribute__((address_space(3))) void*)&Bs[(size_t)(i * 256 + (tid & ~63)) * 16],
          16, 0, 0);
    }
    __syncthreads();                        // staging complete

    f32x16 acc_f[2][2] = {};
    const i32x4 zero4 = {0, 0, 0, 0};
#pragma unroll
    for (int kc = 0; kc < 4; ++kc) {        // four K=64 MFMA chunks
      // fp4: each lane's 32 K-elements = ONE 16B chunk; chunk id = kc*2+khalf
      const int ch = kc * 2 + khalf;
      i32x8 a[2], b[2];
#pragma unroll
      for (int t = 0; t < 2; ++t) {
        int mr = wr * 64 + t * 32 + l31;
        i32x8_pair pa = { *(const i32x4*)&As[mr * RSTRIDE + (ch ^ (mr & 7)) * 16], zero4 };
        a[t] = __builtin_bit_cast(i32x8, pa); // fp4 reads only low 4 regs
        int nr = wc * 64 + t * 32 + l31;
        i32x8_pair pb = { *(const i32x4*)&Bs[nr * RSTRIDE + (ch ^ (nr & 7)) * 16], zero4 };
        b[t] = __builtin_bit_cast(i32x8, pb);
      }
#pragma unroll
      for (int ti = 0; ti < 2; ++ti)
#pragma unroll
        for (int tj = 0; tj < 2; ++tj)
          acc_f[ti][tj] = __builtin_amdgcn_mfma_scale_f32_32x32x64_f8f6f4(
              a[ti], b[tj], acc_f[ti][tj],
              4, 4,                         // FMT: fp4 e2m1 A and B
              0, 0x7B7B7B7B,                // scale_a = 2^-4 (E8M0 123)
              0, 0x7B7B7B7B);               // scale_b = 2^-4
    }

    // per-tile epilogue into per-thread accumulators (weights are linear).
    const bool tdiag = (bi == bj);          // true diagonal tile
    const bool sdiag = (bj == bi + 32);     // (i, i+4096) sim_s tile
    float lsum = 0.0f, dsum = 0.0f;
    if (tdiag || sdiag) {
#pragma unroll
      for (int ti = 0; ti < 2; ++ti)
#pragma unroll
        for (int tj = 0; tj < 2; ++tj)
#pragma unroll
          for (int r = 0; r < 16; ++r) {
            float e = __expf(acc_f[ti][tj][r] * 0.5f);
            lsum += e;
            // 32x32 C/D: col = lane&31, row = (reg&3) + 8*(reg>>2) + 4*khalf
            int row_l = (r & 3) + 8 * (r >> 2) + 4 * khalf;
            if (wr == wc && ti == tj && row_l == l31) dsum += e;
          }
    } else {
#pragma unroll
      for (int ti = 0; ti < 2; ++ti)
#pragma unroll
        for (int tj = 0; tj < 2; ++tj)
#pragma unroll
          for (int r = 0; r < 16; ++r)
            lsum += __expf(acc_f[ti][tj][r] * 0.5f);
    }
    // S gets T_full + all_diag: diag tile adds lsum + its diag extra,
    // off-diag tile counts twice by symmetry.
    Sthr += tdiag ? (lsum + dsum) : 2.0f * lsum;
    if (sdiag) Dthr += dsum;
    __syncthreads();                        // all ds_reads done before restage
  }

  // single block reduction at end of life
#pragma unroll
  for (int off = 32; off > 0; off >>= 1) {
    Sthr += __shfl_xor(Sthr, off, 64);
    Dthr += __shfl_xor(Dthr, off, 64);
  }
  if (lane == 0) { redS[w] = (double)Sthr; redD[w] = (double)Dthr; }
  __syncthreads();
  if (tid == 0) {
    double2 v;
    v.x = redS[0] + redS[1] + redS[2] + redS[3];
    v.y = redD[0] + redD[1] + redD[2] + redD[3];
    partial[blockIdx.x] = v;                // unique slot: plain store, no RMW
  }
}

// ---- kernel 3: reduce 1040 partials, compute the loss. One block.
__global__ __launch_bounds__(256) void reduce_k(const double2* __restrict__ partial,
                                               float* __restrict__ out) {
  __shared__ double redS[4], redD[4];
  double s = 0.0, ss = 0.0;
  for (int i = threadIdx.x; i < GRID2; i += 256) {
    double2 v = partial[i];
    s += v.x; ss += v.y;
  }
#pragma unroll
  for (int off = 32; off > 0; off >>= 1) {
    s  += __shfl_xor(s,  off, 64);
    ss += __shfl_xor(ss, off, 64);
  }
  const int w = threadIdx.x >> 6;
  if ((threadIdx.x & 63) == 0) { redS[w] = s; redD[w] = ss; }
  __syncthreads();
  if (threadIdx.x == 0) {
    double S  = redS[0] + redS[1] + redS[2] + redS[3];
    double sd = redD[0] + redD[1] + redD[2] + redD[3];
    out[0] = (float)(log(0.5 * S + sd) - log(sd));
  }
}

extern "C" void kernel_launch(void* const* d_in, const int* in_sizes, int n_in,
                              void* d_out, int out_size, void* d_ws, size_t ws_size,
                              hipStream_t stream) {
  const float* x    = (const float*)d_in[0];
  unsigned char* z4 = (unsigned char*)d_ws;                  // 8192*128 B = 1 MB
  double2* partial  = (double2*)((char*)d_ws + (size_t)NROWS * RSTRIDE);  // 1040*16 B
  float* out        = (float*)d_out;

  normalize_k<<<dim3(NROWS / 4), dim3(256), 0, stream>>>(x, z4);
  gram_k<<<dim3(GRID2), dim3(256), 0, stream>>>(z4, partial);
  reduce_k<<<dim3(1), dim3(256), 0, stream>>>(partial, out);
}